// Round 9
// baseline (4677.428 us; speedup 1.0000x reference)
//
#include <hip/hip_runtime.h>

#define HID 64
#define TILE 64

__device__ __forceinline__ float silu_f(float x) {
    return x / (1.0f + __expf(-x));
}

// ---------------- input projection: h = nf @ in_w + in_b ----------------
__global__ __launch_bounds__(256)
void in_proj_k(const float* __restrict__ nf, const float* __restrict__ W,
               const float* __restrict__ b, float* __restrict__ h, int Nn)
{
    int t = blockIdx.x * 256 + threadIdx.x;
    if (t >= Nn * HID) return;
    int n = t >> 6, j = t & 63;
    float x0 = nf[n * 3 + 0], x1 = nf[n * 3 + 1], x2 = nf[n * 3 + 2];
    h[t] = fmaf(x0, W[j], fmaf(x1, W[HID + j], fmaf(x2, W[2 * HID + j], b[j])));
}

// ---------------- fused edge message + scatter-add ----------------
// tile of 64 edges, 256 threads. xT in LDS feature-major; 4x4 register tiles.
// yT aliases xT's storage (xT dead after GEMM1) -> 32KB LDS -> 5 blocks/CU.
__global__ __launch_bounds__(256, 4)
void edge_msg_k(const float* __restrict__ h, const int* __restrict__ src,
                const int* __restrict__ dst,
                const float* __restrict__ W1, const float* __restrict__ b1,
                const float* __restrict__ W2, const float* __restrict__ b2,
                float* __restrict__ agg, int E)
{
    __shared__ float xT[2 * HID][TILE];          // 32 KB
    float (*yT)[TILE] = xT;                      // alias: yT rows 0..63 overlay xT rows 0..63

    const int tid = threadIdx.x;
    const int tile0 = blockIdx.x * TILE;

    // ---- gather: 4 threads per edge, float4 loads, transpose into LDS ----
    {
        int eloc = tid >> 2, l4 = tid & 3;
        int e = tile0 + eloc;
        bool ev = e < E;
        int s_n = ev ? src[e] : 0;
        int d_n = ev ? dst[e] : 0;
        const float4* hs = (const float4*)(h + (size_t)s_n * HID);
        const float4* hd = (const float4*)(h + (size_t)d_n * HID);
        #pragma unroll
        for (int k = 0; k < 4; ++k) {
            float4 v = hs[k * 4 + l4];
            float4 w = hd[k * 4 + l4];
            int f = (k * 4 + l4) * 4;
            xT[f + 0][eloc] = v.x; xT[f + 1][eloc] = v.y;
            xT[f + 2][eloc] = v.z; xT[f + 3][eloc] = v.w;
            xT[HID + f + 0][eloc] = w.x; xT[HID + f + 1][eloc] = w.y;
            xT[HID + f + 2][eloc] = w.z; xT[HID + f + 3][eloc] = w.w;
        }
    }
    __syncthreads();

    const int r0 = (tid & 15) * 4;   // edge rows
    const int c0 = (tid >> 4) * 4;   // output cols

    // ---- GEMM1: y = silu(x @ W1 + b1), K = 128 ----
    float acc[4][4];
    {
        float4 bb = *(const float4*)(b1 + c0);
        float bbv[4] = {bb.x, bb.y, bb.z, bb.w};
        #pragma unroll
        for (int rr = 0; rr < 4; ++rr)
            #pragma unroll
            for (int cc = 0; cc < 4; ++cc) acc[rr][cc] = bbv[cc];
    }
    #pragma unroll 8
    for (int i = 0; i < 2 * HID; ++i) {
        float4 a = *(const float4*)&xT[i][r0];
        float4 b = *(const float4*)&W1[i * HID + c0];
        float av[4] = {a.x, a.y, a.z, a.w};
        float bv[4] = {b.x, b.y, b.z, b.w};
        #pragma unroll
        for (int rr = 0; rr < 4; ++rr)
            #pragma unroll
            for (int cc = 0; cc < 4; ++cc)
                acc[rr][cc] = fmaf(av[rr], bv[cc], acc[rr][cc]);
    }
    __syncthreads();   // all GEMM1 reads of xT complete before yT overwrites it
    #pragma unroll
    for (int cc = 0; cc < 4; ++cc)
        #pragma unroll
        for (int rr = 0; rr < 4; ++rr)
            yT[c0 + cc][r0 + rr] = silu_f(acc[rr][cc]);
    __syncthreads();

    // ---- GEMM2: m = y @ W2 + b2, K = 64 ----
    float acc2[4][4];
    {
        float4 bb = *(const float4*)(b2 + c0);
        float bbv[4] = {bb.x, bb.y, bb.z, bb.w};
        #pragma unroll
        for (int rr = 0; rr < 4; ++rr)
            #pragma unroll
            for (int cc = 0; cc < 4; ++cc) acc2[rr][cc] = bbv[cc];
    }
    #pragma unroll 8
    for (int j = 0; j < HID; ++j) {
        float4 a = *(const float4*)&yT[j][r0];
        float4 b = *(const float4*)&W2[j * HID + c0];
        float av[4] = {a.x, a.y, a.z, a.w};
        float bv[4] = {b.x, b.y, b.z, b.w};
        #pragma unroll
        for (int rr = 0; rr < 4; ++rr)
            #pragma unroll
            for (int cc = 0; cc < 4; ++cc)
                acc2[rr][cc] = fmaf(av[rr], bv[cc], acc2[rr][cc]);
    }

    // ---- scatter-add into agg[dst] (dst re-read: L1 broadcast across the 16
    //      threads sharing r0; replaces the dloc[] LDS array) ----
    #pragma unroll
    for (int rr = 0; rr < 4; ++rr) {
        int e2 = tile0 + r0 + rr;
        if (e2 < E) {
            int d = dst[e2];
            float* ap = agg + (size_t)d * HID + c0;
            atomicAdd(ap + 0, acc2[rr][0]);
            atomicAdd(ap + 1, acc2[rr][1]);
            atomicAdd(ap + 2, acc2[rr][2]);
            atomicAdd(ap + 3, acc2[rr][3]);
        }
    }
}

// ---------------- node update: h += MLP([h, agg]) ----------------
__global__ __launch_bounds__(256, 4)
void node_upd_k(float* __restrict__ h, const float* __restrict__ agg,
                const float* __restrict__ W1, const float* __restrict__ b1,
                const float* __restrict__ W2, const float* __restrict__ b2,
                int Nn)
{
    __shared__ float xT[2 * HID][TILE];          // 32 KB
    float (*yT)[TILE] = xT;                      // alias (xT dead after GEMM1)

    const int tid = threadIdx.x;
    const int tile0 = blockIdx.x * TILE;

    {
        int nloc = tid >> 2, l4 = tid & 3;
        int n = tile0 + nloc;
        bool nv = n < Nn;
        size_t base = (size_t)(nv ? n : 0) * HID;
        const float4* hs = (const float4*)(h + base);
        const float4* as = (const float4*)(agg + base);
        #pragma unroll
        for (int k = 0; k < 4; ++k) {
            float4 v = hs[k * 4 + l4];
            float4 w = as[k * 4 + l4];
            int f = (k * 4 + l4) * 4;
            xT[f + 0][nloc] = v.x; xT[f + 1][nloc] = v.y;
            xT[f + 2][nloc] = v.z; xT[f + 3][nloc] = v.w;
            xT[HID + f + 0][nloc] = w.x; xT[HID + f + 1][nloc] = w.y;
            xT[HID + f + 2][nloc] = w.z; xT[HID + f + 3][nloc] = w.w;
        }
    }
    __syncthreads();

    const int r0 = (tid & 15) * 4;
    const int c0 = (tid >> 4) * 4;

    float acc[4][4];
    {
        float4 bb = *(const float4*)(b1 + c0);
        float bbv[4] = {bb.x, bb.y, bb.z, bb.w};
        #pragma unroll
        for (int rr = 0; rr < 4; ++rr)
            #pragma unroll
            for (int cc = 0; cc < 4; ++cc) acc[rr][cc] = bbv[cc];
    }
    #pragma unroll 8
    for (int i = 0; i < 2 * HID; ++i) {
        float4 a = *(const float4*)&xT[i][r0];
        float4 b = *(const float4*)&W1[i * HID + c0];
        float av[4] = {a.x, a.y, a.z, a.w};
        float bv[4] = {b.x, b.y, b.z, b.w};
        #pragma unroll
        for (int rr = 0; rr < 4; ++rr)
            #pragma unroll
            for (int cc = 0; cc < 4; ++cc)
                acc[rr][cc] = fmaf(av[rr], bv[cc], acc[rr][cc]);
    }
    __syncthreads();   // xT reads done before overlay write
    #pragma unroll
    for (int cc = 0; cc < 4; ++cc)
        #pragma unroll
        for (int rr = 0; rr < 4; ++rr)
            yT[c0 + cc][r0 + rr] = silu_f(acc[rr][cc]);
    __syncthreads();

    float acc2[4][4];
    {
        float4 bb = *(const float4*)(b2 + c0);
        float bbv[4] = {bb.x, bb.y, bb.z, bb.w};
        #pragma unroll
        for (int rr = 0; rr < 4; ++rr)
            #pragma unroll
            for (int cc = 0; cc < 4; ++cc) acc2[rr][cc] = bbv[cc];
    }
    #pragma unroll 8
    for (int j = 0; j < HID; ++j) {
        float4 a = *(const float4*)&yT[j][r0];
        float4 b = *(const float4*)&W2[j * HID + c0];
        float av[4] = {a.x, a.y, a.z, a.w};
        float bv[4] = {b.x, b.y, b.z, b.w};
        #pragma unroll
        for (int rr = 0; rr < 4; ++rr)
            #pragma unroll
            for (int cc = 0; cc < 4; ++cc)
                acc2[rr][cc] = fmaf(av[rr], bv[cc], acc2[rr][cc]);
    }

    #pragma unroll
    for (int rr = 0; rr < 4; ++rr) {
        int n2 = tile0 + r0 + rr;
        if (n2 < Nn) {
            float* hp = h + (size_t)n2 * HID + c0;
            hp[0] += acc2[rr][0];
            hp[1] += acc2[rr][1];
            hp[2] += acc2[rr][2];
            hp[3] += acc2[rr][3];
        }
    }
}

// ---------------- readout logits: one wave per node ----------------
__global__ __launch_bounds__(256)
void logits_k(const float* __restrict__ h, const float* __restrict__ W1,
              const float* __restrict__ b1, const float* __restrict__ w2,
              const float* __restrict__ b2, float* __restrict__ lg, int Nn)
{
    int gw = (blockIdx.x * 256 + threadIdx.x) >> 6;
    int lane = threadIdx.x & 63;
    if (gw >= Nn) return;
    const float* hp = h + (size_t)gw * HID;
    float s = b1[lane];
    #pragma unroll 8
    for (int i = 0; i < HID; ++i) s = fmaf(hp[i], W1[i * HID + lane], s);
    float t = silu_f(s) * w2[lane];
    #pragma unroll
    for (int off = 32; off; off >>= 1) t += __shfl_xor(t, off, 64);
    if (lane == 0) lg[gw] = t + b2[0];
}

// ---------------- softmax pieces ----------------
__global__ __launch_bounds__(256)
void rmax_k(const float* __restrict__ x, int n, float* __restrict__ pmax)
{
    __shared__ float sm[4];
    int t = blockIdx.x * 256 + threadIdx.x;
    float v = (t < n) ? x[t] : -1e30f;
    #pragma unroll
    for (int off = 32; off; off >>= 1) v = fmaxf(v, __shfl_xor(v, off, 64));
    int lane = threadIdx.x & 63, w = threadIdx.x >> 6;
    if (lane == 0) sm[w] = v;
    __syncthreads();
    if (threadIdx.x == 0)
        pmax[blockIdx.x] = fmaxf(fmaxf(sm[0], sm[1]), fmaxf(sm[2], sm[3]));
}

__global__ __launch_bounds__(512)
void rmax2_k(const float* __restrict__ p, int nb, float* __restrict__ g)
{
    __shared__ float sm[8];
    int t = threadIdx.x;
    float v = (t < nb) ? p[t] : -1e30f;
    #pragma unroll
    for (int off = 32; off; off >>= 1) v = fmaxf(v, __shfl_xor(v, off, 64));
    int lane = t & 63, w = t >> 6;
    if (lane == 0) sm[w] = v;
    __syncthreads();
    if (t == 0) {
        float m = sm[0];
        #pragma unroll
        for (int i = 1; i < 8; ++i) m = fmaxf(m, sm[i]);
        g[0] = m;
    }
}

__global__ __launch_bounds__(256)
void expsum_k(const float* __restrict__ lg, const float* __restrict__ gmax,
              float* __restrict__ out, float* __restrict__ psum, int n)
{
    __shared__ float sm[4];
    int t = blockIdx.x * 256 + threadIdx.x;
    float gm = gmax[0];
    float v = 0.f;
    if (t < n) { v = __expf(lg[t] - gm); out[t] = v; }
    #pragma unroll
    for (int off = 32; off; off >>= 1) v += __shfl_xor(v, off, 64);
    int lane = threadIdx.x & 63, w = threadIdx.x >> 6;
    if (lane == 0) sm[w] = v;
    __syncthreads();
    if (threadIdx.x == 0)
        psum[blockIdx.x] = (sm[0] + sm[1]) + (sm[2] + sm[3]);
}

__global__ __launch_bounds__(512)
void rsum2_k(const float* __restrict__ p, int nb, float* __restrict__ g)
{
    __shared__ float sm[8];
    int t = threadIdx.x;
    float v = (t < nb) ? p[t] : 0.f;
    #pragma unroll
    for (int off = 32; off; off >>= 1) v += __shfl_xor(v, off, 64);
    int lane = t & 63, w = t >> 6;
    if (lane == 0) sm[w] = v;
    __syncthreads();
    if (t == 0) {
        float s = 0.f;
        #pragma unroll
        for (int i = 0; i < 8; ++i) s += sm[i];
        g[0] = s;
    }
}

__global__ __launch_bounds__(256)
void norm_k(float* __restrict__ out, const float* __restrict__ gsum, int n)
{
    int t = blockIdx.x * 256 + threadIdx.x;
    if (t < n) out[t] = out[t] / gsum[0];
}

extern "C" void kernel_launch(void* const* d_in, const int* in_sizes, int n_in,
                              void* d_out, int out_size, void* d_ws, size_t ws_size,
                              hipStream_t stream)
{
    const float* nf     = (const float*)d_in[0];
    const int*   ei     = (const int*)  d_in[1];
    const float* in_w   = (const float*)d_in[2];
    const float* in_b   = (const float*)d_in[3];
    const float* msg_w1 = (const float*)d_in[4];
    const float* msg_b1 = (const float*)d_in[5];
    const float* msg_w2 = (const float*)d_in[6];
    const float* msg_b2 = (const float*)d_in[7];
    const float* upd_w1 = (const float*)d_in[8];
    const float* upd_b1 = (const float*)d_in[9];
    const float* upd_w2 = (const float*)d_in[10];
    const float* upd_b2 = (const float*)d_in[11];
    const float* ro_w1  = (const float*)d_in[12];
    const float* ro_b1  = (const float*)d_in[13];
    const float* ro_w2  = (const float*)d_in[14];
    const float* ro_b2  = (const float*)d_in[15];

    const int N = in_sizes[0] / 3;
    const int E = in_sizes[1] / 2;
    const int L = in_sizes[4] / (2 * HID * HID);

    const int* src = ei;
    const int* dst = ei + E;

    char* ws = (char*)d_ws;
    const size_t NB = (size_t)N * HID * sizeof(float);
    float* h      = (float*)(ws);
    float* agg    = (float*)(ws + NB);
    size_t lsz = (((size_t)N * sizeof(float)) + 255) & ~(size_t)255;
    float* logits = (float*)(ws + 2 * NB);
    float* pred   = (float*)(ws + 2 * NB + lsz);   // partials (<=1024 floats)
    float* gred   = pred + 1024;                   // [0]=gmax, [1]=gsum

    const int nblk = (N + 255) / 256;

    in_proj_k<<<(N * HID + 255) / 256, 256, 0, stream>>>(nf, in_w, in_b, h, N);

    for (int l = 0; l < L; ++l) {
        hipMemsetAsync(agg, 0, NB, stream);
        edge_msg_k<<<(E + TILE - 1) / TILE, 256, 0, stream>>>(
            h, src, dst,
            msg_w1 + (size_t)l * 2 * HID * HID, msg_b1 + (size_t)l * HID,
            msg_w2 + (size_t)l * HID * HID,     msg_b2 + (size_t)l * HID,
            agg, E);
        node_upd_k<<<(N + TILE - 1) / TILE, 256, 0, stream>>>(
            h, agg,
            upd_w1 + (size_t)l * 2 * HID * HID, upd_b1 + (size_t)l * HID,
            upd_w2 + (size_t)l * HID * HID,     upd_b2 + (size_t)l * HID,
            N);
    }

    logits_k<<<(N + 3) / 4, 256, 0, stream>>>(h, ro_w1, ro_b1, ro_w2, ro_b2, logits, N);

    rmax_k<<<nblk, 256, 0, stream>>>(logits, N, pred);
    rmax2_k<<<1, 512, 0, stream>>>(pred, nblk, gred);
    expsum_k<<<nblk, 256, 0, stream>>>(logits, gred, (float*)d_out, pred, N);
    rsum2_k<<<1, 512, 0, stream>>>(pred, nblk, gred + 1);
    norm_k<<<nblk, 256, 0, stream>>>((float*)d_out, gred + 1, N);
}

// Round 17
// 2419.630 us; speedup vs baseline: 1.9331x; 1.9331x over previous
//
#include <hip/hip_runtime.h>

#define HID 64
#define TILE 64

__device__ __forceinline__ float silu_f(float x) {
    return x / (1.0f + __expf(-x));
}

// ---------------- input projection: h = nf @ in_w + in_b ----------------
__global__ __launch_bounds__(256)
void in_proj_k(const float* __restrict__ nf, const float* __restrict__ W,
               const float* __restrict__ b, float* __restrict__ h, int Nn)
{
    int t = blockIdx.x * 256 + threadIdx.x;
    if (t >= Nn * HID) return;
    int n = t >> 6, j = t & 63;
    float x0 = nf[n * 3 + 0], x1 = nf[n * 3 + 1], x2 = nf[n * 3 + 2];
    h[t] = fmaf(x0, W[j], fmaf(x1, W[HID + j], fmaf(x2, W[2 * HID + j], b[j])));
}

// ---------------- CSR build: histogram -> scan -> permute ----------------
__global__ __launch_bounds__(256)
void hist_k(const int* __restrict__ dst, int* __restrict__ cnt,
            int* __restrict__ rank, int E)
{
    int e = blockIdx.x * 256 + threadIdx.x;
    if (e < E) rank[e] = atomicAdd(&cnt[dst[e]], 1);
}

// per-block exclusive scan of 1024 elements (256 thr x 4), block total -> bsum
__global__ __launch_bounds__(256)
void scan_blk_k(const int* __restrict__ cnt, int* __restrict__ out,
                int* __restrict__ bsum, int n)
{
    __shared__ int s[256];
    int t = threadIdx.x;
    int base = blockIdx.x * 1024 + t * 4;
    int v[4], sum = 0;
    #pragma unroll
    for (int i = 0; i < 4; ++i) {
        int idx = base + i;
        v[i] = (idx < n) ? cnt[idx] : 0;
        sum += v[i];
    }
    s[t] = sum;
    __syncthreads();
    for (int off = 1; off < 256; off <<= 1) {
        int x = (t >= off) ? s[t - off] : 0;
        __syncthreads();
        s[t] += x;
        __syncthreads();
    }
    if (t == 255) bsum[blockIdx.x] = s[255];
    int run = s[t] - sum;  // exclusive prefix of this thread's chunk
    #pragma unroll
    for (int i = 0; i < 4; ++i) {
        int idx = base + i;
        if (idx < n) out[idx] = run;
        run += v[i];
    }
}

// single-block exclusive scan of block sums (nb <= 128)
__global__ __launch_bounds__(128)
void scan_top_k(int* __restrict__ bsum, int nb)
{
    __shared__ int s[128];
    int t = threadIdx.x;
    int v = (t < nb) ? bsum[t] : 0;
    s[t] = v;
    __syncthreads();
    for (int off = 1; off < 128; off <<= 1) {
        int x = (t >= off) ? s[t - off] : 0;
        __syncthreads();
        s[t] += x;
        __syncthreads();
    }
    if (t < nb) bsum[t] = s[t] - v;  // exclusive
}

__global__ __launch_bounds__(256)
void scan_add_k(int* __restrict__ out, const int* __restrict__ bsum, int n)
{
    int i = blockIdx.x * 256 + threadIdx.x;
    if (i < n) out[i] += bsum[i >> 10];
}

__global__ __launch_bounds__(256)
void perm_k(const int* __restrict__ src, const int* __restrict__ dst,
            const int* __restrict__ rank, const int* __restrict__ row_ptr,
            int* __restrict__ s_src, int* __restrict__ s_dst, int E)
{
    int e = blockIdx.x * 256 + threadIdx.x;
    if (e < E) {
        int d = dst[e];
        int p = row_ptr[d] + rank[e];
        s_src[p] = src[e];
        s_dst[p] = d;
    }
}

// ---------------- fused edge message + segment-reduced scatter ----------------
// Edges pre-sorted by dst. Tile of 64 sorted edges, 256 threads.
// xT[0:128) staging; yT overlays rows 0:64 after GEMM1; mT overlays rows 64:128
// after GEMM1. Per-column segment scan emits ~1 atomic per distinct dst per col.
__global__ __launch_bounds__(256, 4)
void edge_msg_s_k(const float* __restrict__ h, const int* __restrict__ s_src,
                  const int* __restrict__ s_dst,
                  const float* __restrict__ W1, const float* __restrict__ b1,
                  const float* __restrict__ W2, const float* __restrict__ b2,
                  float* __restrict__ agg, int E)
{
    __shared__ float xT[2 * HID][TILE];          // 32 KB
    __shared__ int sd[TILE];
    float (*yT)[TILE] = xT;                      // rows 0..63 (post-GEMM1)
    float (*mT)[TILE] = xT + HID;                // rows 64..127 (post-GEMM1)

    const int tid = threadIdx.x;
    const int tile0 = blockIdx.x * TILE;

    // ---- gather (sorted edges: dst rows highly L1-local) ----
    {
        int eloc = tid >> 2, l4 = tid & 3;
        int e = tile0 + eloc;
        bool ev = e < E;
        int s_n = ev ? s_src[e] : 0;
        int d_n = ev ? s_dst[e] : 0;
        if (l4 == 0) sd[eloc] = ev ? d_n : -1;
        const float4* hs = (const float4*)(h + (size_t)s_n * HID);
        const float4* hd = (const float4*)(h + (size_t)d_n * HID);
        #pragma unroll
        for (int k = 0; k < 4; ++k) {
            float4 v = hs[k * 4 + l4];
            float4 w = hd[k * 4 + l4];
            int f = (k * 4 + l4) * 4;
            xT[f + 0][eloc] = v.x; xT[f + 1][eloc] = v.y;
            xT[f + 2][eloc] = v.z; xT[f + 3][eloc] = v.w;
            xT[HID + f + 0][eloc] = w.x; xT[HID + f + 1][eloc] = w.y;
            xT[HID + f + 2][eloc] = w.z; xT[HID + f + 3][eloc] = w.w;
        }
    }
    __syncthreads();

    const int r0 = (tid & 15) * 4;   // edge rows
    const int c0 = (tid >> 4) * 4;   // output cols

    // ---- GEMM1: y = silu(x @ W1 + b1), K = 128 ----
    float acc[4][4];
    {
        float4 bb = *(const float4*)(b1 + c0);
        float bbv[4] = {bb.x, bb.y, bb.z, bb.w};
        #pragma unroll
        for (int rr = 0; rr < 4; ++rr)
            #pragma unroll
            for (int cc = 0; cc < 4; ++cc) acc[rr][cc] = bbv[cc];
    }
    #pragma unroll 8
    for (int i = 0; i < 2 * HID; ++i) {
        float4 a = *(const float4*)&xT[i][r0];
        float4 b = *(const float4*)&W1[i * HID + c0];
        float av[4] = {a.x, a.y, a.z, a.w};
        float bv[4] = {b.x, b.y, b.z, b.w};
        #pragma unroll
        for (int rr = 0; rr < 4; ++rr)
            #pragma unroll
            for (int cc = 0; cc < 4; ++cc)
                acc[rr][cc] = fmaf(av[rr], bv[cc], acc[rr][cc]);
    }
    __syncthreads();   // all GEMM1 reads of xT done before overlay writes
    #pragma unroll
    for (int cc = 0; cc < 4; ++cc)
        #pragma unroll
        for (int rr = 0; rr < 4; ++rr)
            yT[c0 + cc][r0 + rr] = silu_f(acc[rr][cc]);
    __syncthreads();

    // ---- GEMM2: m = y @ W2 + b2, K = 64 ----
    float acc2[4][4];
    {
        float4 bb = *(const float4*)(b2 + c0);
        float bbv[4] = {bb.x, bb.y, bb.z, bb.w};
        #pragma unroll
        for (int rr = 0; rr < 4; ++rr)
            #pragma unroll
            for (int cc = 0; cc < 4; ++cc) acc2[rr][cc] = bbv[cc];
    }
    #pragma unroll 8
    for (int j = 0; j < HID; ++j) {
        float4 a = *(const float4*)&yT[j][r0];
        float4 b = *(const float4*)&W2[j * HID + c0];
        float av[4] = {a.x, a.y, a.z, a.w};
        float bv[4] = {b.x, b.y, b.z, b.w};
        #pragma unroll
        for (int rr = 0; rr < 4; ++rr)
            #pragma unroll
            for (int cc = 0; cc < 4; ++cc)
                acc2[rr][cc] = fmaf(av[rr], bv[cc], acc2[rr][cc]);
    }

    // ---- stash messages to mT (rows 64..127, dead after GEMM1) ----
    #pragma unroll
    for (int rr = 0; rr < 4; ++rr)
        #pragma unroll
        for (int cc = 0; cc < 4; ++cc)
            mT[r0 + rr][c0 + cc] = acc2[rr][cc];
    __syncthreads();

    // ---- per-column segment reduce over sorted dst; 1 atomic per run ----
    if (tid < TILE) {
        int c = tid;
        float run = 0.f;
        int cur = -2;
        #pragma unroll 8
        for (int r = 0; r < TILE; ++r) {
            int d = sd[r];
            float val = mT[r][c];
            if (d != cur) {
                if (cur >= 0) atomicAdd(&agg[(size_t)cur * HID + c], run);
                cur = d;
                run = 0.f;
            }
            if (d >= 0) run += val;
        }
        if (cur >= 0) atomicAdd(&agg[(size_t)cur * HID + c], run);
    }
}

// ---------------- node update: h += MLP([h, agg]) ----------------
__global__ __launch_bounds__(256, 4)
void node_upd_k(float* __restrict__ h, const float* __restrict__ agg,
                const float* __restrict__ W1, const float* __restrict__ b1,
                const float* __restrict__ W2, const float* __restrict__ b2,
                int Nn)
{
    __shared__ float xT[2 * HID][TILE];          // 32 KB
    float (*yT)[TILE] = xT;                      // alias (xT dead after GEMM1)

    const int tid = threadIdx.x;
    const int tile0 = blockIdx.x * TILE;

    {
        int nloc = tid >> 2, l4 = tid & 3;
        int n = tile0 + nloc;
        bool nv = n < Nn;
        size_t base = (size_t)(nv ? n : 0) * HID;
        const float4* hs = (const float4*)(h + base);
        const float4* as = (const float4*)(agg + base);
        #pragma unroll
        for (int k = 0; k < 4; ++k) {
            float4 v = hs[k * 4 + l4];
            float4 w = as[k * 4 + l4];
            int f = (k * 4 + l4) * 4;
            xT[f + 0][nloc] = v.x; xT[f + 1][nloc] = v.y;
            xT[f + 2][nloc] = v.z; xT[f + 3][nloc] = v.w;
            xT[HID + f + 0][nloc] = w.x; xT[HID + f + 1][nloc] = w.y;
            xT[HID + f + 2][nloc] = w.z; xT[HID + f + 3][nloc] = w.w;
        }
    }
    __syncthreads();

    const int r0 = (tid & 15) * 4;
    const int c0 = (tid >> 4) * 4;

    float acc[4][4];
    {
        float4 bb = *(const float4*)(b1 + c0);
        float bbv[4] = {bb.x, bb.y, bb.z, bb.w};
        #pragma unroll
        for (int rr = 0; rr < 4; ++rr)
            #pragma unroll
            for (int cc = 0; cc < 4; ++cc) acc[rr][cc] = bbv[cc];
    }
    #pragma unroll 8
    for (int i = 0; i < 2 * HID; ++i) {
        float4 a = *(const float4*)&xT[i][r0];
        float4 b = *(const float4*)&W1[i * HID + c0];
        float av[4] = {a.x, a.y, a.z, a.w};
        float bv[4] = {b.x, b.y, b.z, b.w};
        #pragma unroll
        for (int rr = 0; rr < 4; ++rr)
            #pragma unroll
            for (int cc = 0; cc < 4; ++cc)
                acc[rr][cc] = fmaf(av[rr], bv[cc], acc[rr][cc]);
    }
    __syncthreads();   // xT reads done before overlay write
    #pragma unroll
    for (int cc = 0; cc < 4; ++cc)
        #pragma unroll
        for (int rr = 0; rr < 4; ++rr)
            yT[c0 + cc][r0 + rr] = silu_f(acc[rr][cc]);
    __syncthreads();

    float acc2[4][4];
    {
        float4 bb = *(const float4*)(b2 + c0);
        float bbv[4] = {bb.x, bb.y, bb.z, bb.w};
        #pragma unroll
        for (int rr = 0; rr < 4; ++rr)
            #pragma unroll
            for (int cc = 0; cc < 4; ++cc) acc2[rr][cc] = bbv[cc];
    }
    #pragma unroll 8
    for (int j = 0; j < HID; ++j) {
        float4 a = *(const float4*)&yT[j][r0];
        float4 b = *(const float4*)&W2[j * HID + c0];
        float av[4] = {a.x, a.y, a.z, a.w};
        float bv[4] = {b.x, b.y, b.z, b.w};
        #pragma unroll
        for (int rr = 0; rr < 4; ++rr)
            #pragma unroll
            for (int cc = 0; cc < 4; ++cc)
                acc2[rr][cc] = fmaf(av[rr], bv[cc], acc2[rr][cc]);
    }

    #pragma unroll
    for (int rr = 0; rr < 4; ++rr) {
        int n2 = tile0 + r0 + rr;
        if (n2 < Nn) {
            float* hp = h + (size_t)n2 * HID + c0;
            hp[0] += acc2[rr][0];
            hp[1] += acc2[rr][1];
            hp[2] += acc2[rr][2];
            hp[3] += acc2[rr][3];
        }
    }
}

// ---------------- readout logits: one wave per node ----------------
__global__ __launch_bounds__(256)
void logits_k(const float* __restrict__ h, const float* __restrict__ W1,
              const float* __restrict__ b1, const float* __restrict__ w2,
              const float* __restrict__ b2, float* __restrict__ lg, int Nn)
{
    int gw = (blockIdx.x * 256 + threadIdx.x) >> 6;
    int lane = threadIdx.x & 63;
    if (gw >= Nn) return;
    const float* hp = h + (size_t)gw * HID;
    float s = b1[lane];
    #pragma unroll 8
    for (int i = 0; i < HID; ++i) s = fmaf(hp[i], W1[i * HID + lane], s);
    float t = silu_f(s) * w2[lane];
    #pragma unroll
    for (int off = 32; off; off >>= 1) t += __shfl_xor(t, off, 64);
    if (lane == 0) lg[gw] = t + b2[0];
}

// ---------------- softmax pieces ----------------
__global__ __launch_bounds__(256)
void rmax_k(const float* __restrict__ x, int n, float* __restrict__ pmax)
{
    __shared__ float sm[4];
    int t = blockIdx.x * 256 + threadIdx.x;
    float v = (t < n) ? x[t] : -1e30f;
    #pragma unroll
    for (int off = 32; off; off >>= 1) v = fmaxf(v, __shfl_xor(v, off, 64));
    int lane = threadIdx.x & 63, w = threadIdx.x >> 6;
    if (lane == 0) sm[w] = v;
    __syncthreads();
    if (threadIdx.x == 0)
        pmax[blockIdx.x] = fmaxf(fmaxf(sm[0], sm[1]), fmaxf(sm[2], sm[3]));
}

__global__ __launch_bounds__(512)
void rmax2_k(const float* __restrict__ p, int nb, float* __restrict__ g)
{
    __shared__ float sm[8];
    int t = threadIdx.x;
    float v = (t < nb) ? p[t] : -1e30f;
    #pragma unroll
    for (int off = 32; off; off >>= 1) v = fmaxf(v, __shfl_xor(v, off, 64));
    int lane = t & 63, w = t >> 6;
    if (lane == 0) sm[w] = v;
    __syncthreads();
    if (t == 0) {
        float m = sm[0];
        #pragma unroll
        for (int i = 1; i < 8; ++i) m = fmaxf(m, sm[i]);
        g[0] = m;
    }
}

__global__ __launch_bounds__(256)
void expsum_k(const float* __restrict__ lg, const float* __restrict__ gmax,
              float* __restrict__ out, float* __restrict__ psum, int n)
{
    __shared__ float sm[4];
    int t = blockIdx.x * 256 + threadIdx.x;
    float gm = gmax[0];
    float v = 0.f;
    if (t < n) { v = __expf(lg[t] - gm); out[t] = v; }
    #pragma unroll
    for (int off = 32; off; off >>= 1) v += __shfl_xor(v, off, 64);
    int lane = threadIdx.x & 63, w = threadIdx.x >> 6;
    if (lane == 0) sm[w] = v;
    __syncthreads();
    if (threadIdx.x == 0)
        psum[blockIdx.x] = (sm[0] + sm[1]) + (sm[2] + sm[3]);
}

__global__ __launch_bounds__(512)
void rsum2_k(const float* __restrict__ p, int nb, float* __restrict__ g)
{
    __shared__ float sm[8];
    int t = threadIdx.x;
    float v = (t < nb) ? p[t] : 0.f;
    #pragma unroll
    for (int off = 32; off; off >>= 1) v += __shfl_xor(v, off, 64);
    int lane = t & 63, w = t >> 6;
    if (lane == 0) sm[w] = v;
    __syncthreads();
    if (t == 0) {
        float s = 0.f;
        #pragma unroll
        for (int i = 0; i < 8; ++i) s += sm[i];
        g[0] = s;
    }
}

__global__ __launch_bounds__(256)
void norm_k(float* __restrict__ out, const float* __restrict__ gsum, int n)
{
    int t = blockIdx.x * 256 + threadIdx.x;
    if (t < n) out[t] = out[t] / gsum[0];
}

extern "C" void kernel_launch(void* const* d_in, const int* in_sizes, int n_in,
                              void* d_out, int out_size, void* d_ws, size_t ws_size,
                              hipStream_t stream)
{
    const float* nf     = (const float*)d_in[0];
    const int*   ei     = (const int*)  d_in[1];
    const float* in_w   = (const float*)d_in[2];
    const float* in_b   = (const float*)d_in[3];
    const float* msg_w1 = (const float*)d_in[4];
    const float* msg_b1 = (const float*)d_in[5];
    const float* msg_w2 = (const float*)d_in[6];
    const float* msg_b2 = (const float*)d_in[7];
    const float* upd_w1 = (const float*)d_in[8];
    const float* upd_b1 = (const float*)d_in[9];
    const float* upd_w2 = (const float*)d_in[10];
    const float* upd_b2 = (const float*)d_in[11];
    const float* ro_w1  = (const float*)d_in[12];
    const float* ro_b1  = (const float*)d_in[13];
    const float* ro_w2  = (const float*)d_in[14];
    const float* ro_b2  = (const float*)d_in[15];

    const int N = in_sizes[0] / 3;
    const int E = in_sizes[1] / 2;
    const int L = in_sizes[4] / (2 * HID * HID);

    const int* src = ei;
    const int* dst = ei + E;

    // ---- workspace layout (all offsets 256B-aligned) ----
    char* ws = (char*)d_ws;
    const size_t NB = (size_t)N * HID * sizeof(float);          // 25.6 MB
    const size_t lsz = (((size_t)N * sizeof(float)) + 255) & ~(size_t)255;
    const size_t isz = (((size_t)E * sizeof(int)) + 255) & ~(size_t)255;
    const size_t nsz = (((size_t)(N + 1) * sizeof(int)) + 255) & ~(size_t)255;

    float* h      = (float*)(ws);
    float* agg    = (float*)(ws + NB);
    float* logits = (float*)(ws + 2 * NB);
    float* pred   = (float*)(ws + 2 * NB + lsz);          // partials
    float* gred   = pred + 1024;                          // [0]=gmax, [1]=gsum
    char*  ip     = ws + 2 * NB + lsz + 256 * 256;        // int region
    int* cnt      = (int*)(ip);
    int* row_ptr  = (int*)(ip + nsz);
    int* rank     = (int*)(ip + 2 * nsz);
    int* s_src    = (int*)(ip + 2 * nsz + isz);
    int* s_dst    = (int*)(ip + 2 * nsz + 2 * isz);
    int* bsum     = (int*)(ip + 2 * nsz + 3 * isz);       // 128 ints

    const int nblk   = (N + 255) / 256;
    const int eblk   = (E + 255) / 256;
    const int nbscan = (N + 1023) / 1024;                 // 98 <= 128

    // ---- CSR build (once per call; edge_index constant across layers) ----
    hipMemsetAsync(cnt, 0, (size_t)N * sizeof(int), stream);
    hist_k<<<eblk, 256, 0, stream>>>(dst, cnt, rank, E);
    scan_blk_k<<<nbscan, 256, 0, stream>>>(cnt, row_ptr, bsum, N);
    scan_top_k<<<1, 128, 0, stream>>>(bsum, nbscan);
    scan_add_k<<<nblk, 256, 0, stream>>>(row_ptr, bsum, N);
    perm_k<<<eblk, 256, 0, stream>>>(src, dst, rank, row_ptr, s_src, s_dst, E);

    in_proj_k<<<(N * HID + 255) / 256, 256, 0, stream>>>(nf, in_w, in_b, h, N);

    for (int l = 0; l < L; ++l) {
        hipMemsetAsync(agg, 0, NB, stream);
        edge_msg_s_k<<<(E + TILE - 1) / TILE, 256, 0, stream>>>(
            h, s_src, s_dst,
            msg_w1 + (size_t)l * 2 * HID * HID, msg_b1 + (size_t)l * HID,
            msg_w2 + (size_t)l * HID * HID,     msg_b2 + (size_t)l * HID,
            agg, E);
        node_upd_k<<<(N + TILE - 1) / TILE, 256, 0, stream>>>(
            h, agg,
            upd_w1 + (size_t)l * 2 * HID * HID, upd_b1 + (size_t)l * HID,
            upd_w2 + (size_t)l * HID * HID,     upd_b2 + (size_t)l * HID,
            N);
    }

    logits_k<<<(N + 3) / 4, 256, 0, stream>>>(h, ro_w1, ro_b1, ro_w2, ro_b2, logits, N);

    rmax_k<<<nblk, 256, 0, stream>>>(logits, N, pred);
    rmax2_k<<<1, 512, 0, stream>>>(pred, nblk, gred);
    expsum_k<<<nblk, 256, 0, stream>>>(logits, gred, (float*)d_out, pred, N);
    rsum2_k<<<1, 512, 0, stream>>>(pred, nblk, gred + 1);
    norm_k<<<nblk, 256, 0, stream>>>((float*)d_out, gred + 1, N);
}